// Round 1
// baseline (788.798 us; speedup 1.0000x reference)
//
#include <hip/hip_runtime.h>
#include <math.h>

// Problem constants
#define BB 8
#define NN 4096
#define DD 1024
#define NC 512
#define HALF 512          // D/2
#define DQ 256            // D/4
#define H1 512            // hidden = D/2
#define M_TOT (BB*NN)     // 32768 token rows
#define MIN_ACTIVE 819    // int(4096*0.2)

// ---------------- K0: detect rare_mask storage format ----------------
// mode 0 = int32, 1 = uint8 (numpy bool), 2 = float32
__global__ void detect_mask_kernel(const unsigned char* __restrict__ p, int* __restrict__ mode) {
    __shared__ int nonbin, oneoff;
    if (threadIdx.x == 0) { nonbin = 0; oneoff = 0; }
    __syncthreads();
    int lnon = 0, lone = 0;
    // scan first 32768 bytes (valid for all three candidate layouts)
    for (int i = threadIdx.x; i < 32768; i += blockDim.x) {
        unsigned char b = p[i];
        if (b > 1) lnon = 1;
        else if (b == 1 && (i & 3) != 0) lone = 1;
    }
    if (lnon) atomicOr(&nonbin, 1);
    if (lone) atomicOr(&oneoff, 1);
    __syncthreads();
    if (threadIdx.x == 0) *mode = nonbin ? 2 : (oneoff ? 1 : 0);
}

// ---------------- K1: ctx mean over NC tokens ----------------
__global__ void ctx_mean_kernel(const float* __restrict__ ctx, float* __restrict__ out) {
    int idx = blockIdx.x * blockDim.x + threadIdx.x; // 8192 = B*D
    int b = idx >> 10, d = idx & 1023;
    const float* base = ctx + ((size_t)b * NC) * DD + d;
    double acc = 0.0;
    for (int n = 0; n < NC; ++n) acc += (double)base[(size_t)n * DD];
    out[idx] = (float)(acc * (1.0 / NC));
}

// ---------------- K2: ctx_bn = mean @ ctx_w + ctx_b ----------------
__global__ void ctx_bn_kernel(const float* __restrict__ mean, const float* __restrict__ w,
                              const float* __restrict__ bias, float* __restrict__ out) {
    int b = blockIdx.x, j = threadIdx.x; // 256 threads
    double acc = (double)bias[j];
    const float* mb = mean + b * DD;
    for (int k = 0; k < DD; ++k) acc += (double)mb[k] * (double)w[(size_t)k * DQ + j];
    out[b * DQ + j] = (float)acc;
}

// ---------------- K3: t_emb = [sin,cos](t*freq) @ t_proj_w + t_proj_b ----------------
__global__ void temb_kernel(const int* __restrict__ tvals, const float* __restrict__ w,
                            const float* __restrict__ bias, float* __restrict__ out) {
    __shared__ double emb[DD];
    int b = blockIdx.x, tid = threadIdx.x; // 256 threads
    double t = (double)tvals[b];
    const double neg_ln = -log(10000.0) / 511.0;
    for (int j = tid; j < DD; j += 256) {
        int jj = (j < HALF) ? j : (j - HALF);
        double arg = t * exp(neg_ln * (double)jj);
        emb[j] = (j < HALF) ? sin(arg) : cos(arg);
    }
    __syncthreads();
    for (int m = 0; m < 4; ++m) {
        int col = tid + 256 * m;
        double acc = (double)bias[col];
        for (int k = 0; k < DD; ++k) acc += emb[k] * (double)w[(size_t)k * DD + col];
        out[b * DD + col] = (float)acc;
    }
}

// ---------------- K4: base_h = b1 + ctx_bn@w1[1024:1280] + t_emb@w1[1280:2304] ----------------
__global__ void baseh_kernel(const float* __restrict__ ctx_bn, const float* __restrict__ temb,
                             const float* __restrict__ w1, const float* __restrict__ b1,
                             float* __restrict__ out) {
    int b = blockIdx.x, j = threadIdx.x; // 512 threads
    double acc = (double)b1[j];
    const float* cb = ctx_bn + b * DQ;
    const float* te = temb + b * DD;
    for (int k = 0; k < DQ; ++k) acc += (double)cb[k] * (double)w1[(size_t)(1024 + k) * H1 + j];
    for (int k = 0; k < DD; ++k) acc += (double)te[k] * (double)w1[(size_t)(1280 + k) * H1 + j];
    out[b * H1 + j] = (float)acc;
}

// ---------------- K5: big GEMM tokens@w1_top, fused relu + w2 partial reduce ----------------
// BM=64 rows, BN=64 cols, BK=16. 256 threads, 4x4 micro-tile. 8 col-blocks -> partials.
#define BM 64
#define BN 64
#define BK 16
__global__ __launch_bounds__(256) void gemm_kernel(
    const float* __restrict__ tokens, const float* __restrict__ w1,
    const float* __restrict__ baseh, const float* __restrict__ w2,
    float* __restrict__ part) {
    __shared__ float As[BK][BM + 4]; // transposed A tile, stride 68 floats (16B aligned)
    __shared__ float Bs[BK][BN];
    int tid = threadIdx.x;
    int tx = tid & 15, ty = tid >> 4;
    int row0 = blockIdx.x * BM;
    int col0 = blockIdx.y * BN;
    const float* Ap = tokens + (size_t)row0 * DD;
    const float* Bp = w1 + col0;
    float acc[4][4] = {};

    for (int kt = 0; kt < DD; kt += BK) {
        // stage A (64x16) transposed: lane reads 4 rows' worth, coalesced-ish along k
        {
            int k = tid & 15, m = tid >> 4;
            #pragma unroll
            for (int i = 0; i < 4; ++i)
                As[k][m + 16 * i] = Ap[(size_t)(m + 16 * i) * DD + kt + k];
        }
        // stage B (16x64): coalesced 256B rows
        {
            int j = tid & 63;
            #pragma unroll
            for (int i = 0; i < 4; ++i) {
                int kk = (tid >> 6) + 4 * i;
                Bs[kk][j] = Bp[(size_t)(kt + kk) * H1 + j];
            }
        }
        __syncthreads();
        #pragma unroll
        for (int k = 0; k < BK; ++k) {
            float4 a = *reinterpret_cast<const float4*>(&As[k][ty * 4]);
            float4 b = *reinterpret_cast<const float4*>(&Bs[k][tx * 4]);
            float av[4] = {a.x, a.y, a.z, a.w};
            float bv[4] = {b.x, b.y, b.z, b.w};
            #pragma unroll
            for (int i = 0; i < 4; ++i)
                #pragma unroll
                for (int j = 0; j < 4; ++j)
                    acc[i][j] += av[i] * bv[j];
        }
        __syncthreads();
    }

    // epilogue: relu + w2-weighted partial sum over this col-block
    int b = row0 >> 12; // batch (4096 rows per batch, BM divides 4096)
    const float* bh = baseh + b * H1;
    float pm[4];
    #pragma unroll
    for (int i = 0; i < 4; ++i) {
        float p = 0.f;
        #pragma unroll
        for (int j = 0; j < 4; ++j) {
            int col = col0 + tx * 4 + j;
            float h = acc[i][j] + bh[col];
            h = h > 0.f ? h : 0.f;
            p += h * w2[col];
        }
        pm[i] = p;
    }
    // reduce across tx (16 lanes within each row group)
    #pragma unroll
    for (int off = 1; off < 16; off <<= 1)
        #pragma unroll
        for (int i = 0; i < 4; ++i)
            pm[i] += __shfl_xor(pm[i], off, 64);
    if (tx == 0) {
        #pragma unroll
        for (int i = 0; i < 4; ++i)
            part[(size_t)(row0 + ty * 4 + i) * 8 + blockIdx.y] = pm[i];
    }
}

// ---------------- K6: reduce partials -> logit -> score + pre-floor skip ----------------
__global__ void score_kernel(const float* __restrict__ part, const float* __restrict__ b2,
                             const void* __restrict__ rare, const int* __restrict__ mode_p,
                             float* __restrict__ out) {
    int row = blockIdx.x * blockDim.x + threadIdx.x; // 32768
    float logit = b2[0];
    #pragma unroll
    for (int p = 0; p < 8; ++p) logit += part[(size_t)row * 8 + p];
    float score = 1.f / (1.f + expf(-logit));
    int mode = *mode_p;
    bool rm;
    if (mode == 1)      rm = ((const unsigned char*)rare)[row] != 0;
    else if (mode == 2) rm = ((const float*)rare)[row] != 0.f;
    else                rm = ((const int*)rare)[row] != 0;
    bool skip = (score > 0.5f) && !rm;
    out[row] = skip ? 1.f : 0.f;
    out[M_TOT + row] = score;
}

// ---------------- K7: 20% active-floor correction (per batch) ----------------
__global__ void floor_kernel(float* __restrict__ out) {
    __shared__ float s[NN];
    __shared__ unsigned char f[NN];
    __shared__ int cnt;
    int b = blockIdx.x, tid = threadIdx.x;
    if (tid == 0) cnt = 0;
    __syncthreads();
    int local = 0;
    for (int i = tid; i < NN; i += 256) {
        s[i] = out[M_TOT + b * NN + i];
        unsigned char sk = out[b * NN + i] > 0.5f;
        f[i] = sk;
        local += sk;
    }
    atomicAdd(&cnt, local);
    __syncthreads();
    int deficit = cnt - (NN - MIN_ACTIVE); // = MIN_ACTIVE - active
    if (deficit <= 0) return;
    // unskip the `deficit` lowest-(score,idx) skipped tokens (stable-rank semantics)
    for (int i = tid; i < NN; i += 256) {
        if (!f[i]) continue;
        float si = s[i];
        int rank = 0;
        for (int j = 0; j < NN; ++j) {
            if (f[j] && (s[j] < si || (s[j] == si && j < i))) {
                if (++rank >= deficit) break;
            }
        }
        if (rank < deficit) out[b * NN + i] = 0.f;
    }
}

extern "C" void kernel_launch(void* const* d_in, const int* in_sizes, int n_in,
                              void* d_out, int out_size, void* d_ws, size_t ws_size,
                              hipStream_t stream) {
    const float* tokens   = (const float*)d_in[0];
    const float* ctx_C    = (const float*)d_in[1];
    const int*   t        = (const int*)d_in[2];
    const void*  rare     = d_in[3];
    const float* ctx_w    = (const float*)d_in[4];
    const float* ctx_b    = (const float*)d_in[5];
    const float* t_proj_w = (const float*)d_in[6];
    const float* t_proj_b = (const float*)d_in[7];
    const float* w1       = (const float*)d_in[8];
    const float* b1       = (const float*)d_in[9];
    const float* w2       = (const float*)d_in[10];
    const float* b2       = (const float*)d_in[11];
    float* out = (float*)d_out;

    // workspace layout (floats)
    int*   mode     = (int*)d_ws;
    float* wsf      = (float*)d_ws;
    float* ctx_mean = wsf + 64;             // 8192
    float* ctx_bn   = ctx_mean + 8192;      // 2048
    float* t_emb    = ctx_bn + 2048;        // 8192
    float* base_h   = t_emb + 8192;         // 4096
    float* part     = base_h + 4096;        // 262144  (~1.1 MB total)

    detect_mask_kernel<<<1, 256, 0, stream>>>((const unsigned char*)rare, mode);
    ctx_mean_kernel<<<32, 256, 0, stream>>>(ctx_C, ctx_mean);
    ctx_bn_kernel<<<BB, 256, 0, stream>>>(ctx_mean, ctx_w, ctx_b, ctx_bn);
    temb_kernel<<<BB, 256, 0, stream>>>(t, t_proj_w, t_proj_b, t_emb);
    baseh_kernel<<<BB, 512, 0, stream>>>(ctx_bn, t_emb, w1, b1, base_h);
    gemm_kernel<<<dim3(M_TOT / BM, H1 / BN), 256, 0, stream>>>(tokens, w1, base_h, w2, part);
    score_kernel<<<M_TOT / 256, 256, 0, stream>>>(part, b2, rare, mode, out);
    floor_kernel<<<BB, 256, 0, stream>>>(out);
}

// Round 2
// 388.315 us; speedup vs baseline: 2.0313x; 2.0313x over previous
//
#include <hip/hip_runtime.h>
#include <math.h>

#define NN 4096
#define DD 1024
#define M_TOT 32768
#define H1 512
#define MIN_ACTIVE 819
#define MARGIN 0.03f

typedef __bf16 bf16x8 __attribute__((ext_vector_type(8)));
typedef float f32x4 __attribute__((ext_vector_type(4)));

__device__ __forceinline__ unsigned short f2bf(float f) {
    unsigned int u = __float_as_uint(f);
    return (unsigned short)((u + 0x7FFFu + ((u >> 16) & 1u)) >> 16);
}

// ---------------- K0: detect rare_mask storage format ----------------
__global__ void detect_mask_kernel(const unsigned char* __restrict__ p, int* __restrict__ mode) {
    __shared__ int nonbin, oneoff;
    if (threadIdx.x == 0) { nonbin = 0; oneoff = 0; }
    __syncthreads();
    int lnon = 0, lone = 0;
    for (int i = threadIdx.x; i < 32768; i += blockDim.x) {
        unsigned char b = p[i];
        if (b > 1) lnon = 1;
        else if (b == 1 && (i & 3) != 0) lone = 1;
    }
    if (lnon) atomicOr(&nonbin, 1);
    if (lone) atomicOr(&oneoff, 1);
    __syncthreads();
    if (threadIdx.x == 0) *mode = nonbin ? 2 : (oneoff ? 1 : 0);
}

// ---------------- K1: transpose+convert w1[0:1024][:512] -> bf16 [512][1024] ----------------
__global__ void convB_kernel(const float* __restrict__ w1, unsigned short* __restrict__ w1t) {
    __shared__ float tile[32][33];
    int k0 = (blockIdx.x >> 4) * 32;
    int c0 = (blockIdx.x & 15) * 32;
    int tid = threadIdx.x;
    int cl = tid & 31, r8 = tid >> 5;
    #pragma unroll
    for (int i = 0; i < 4; ++i) {
        int kl = r8 + 8 * i;
        tile[kl][cl] = w1[(size_t)(k0 + kl) * H1 + c0 + cl];
    }
    __syncthreads();
    #pragma unroll
    for (int i = 0; i < 4; ++i) {
        int cr = r8 + 8 * i;
        w1t[(size_t)(c0 + cr) * DD + k0 + cl] = f2bf(tile[cl][cr]);
    }
}

// ---------------- K2a: partial ctx mean ----------------
__global__ void pmean_kernel(const float* __restrict__ ctx, float* __restrict__ pmean) {
    int blk = blockIdx.x; // 256 = 8b * 4dq * 8nz
    int b = blk >> 5, dq = (blk >> 3) & 3, nz = blk & 7;
    int d = dq * 256 + threadIdx.x;
    const float* base = ctx + ((size_t)(b * 512 + nz * 64)) * DD + d;
    float acc = 0.f;
    for (int n = 0; n < 64; ++n) acc += base[(size_t)n * DD];
    pmean[(b * 8 + nz) * DD + d] = acc;
}

// ---------------- K2b: reduce partials -> mean ----------------
__global__ void meanred_kernel(const float* __restrict__ pmean, float* __restrict__ mean) {
    int idx = blockIdx.x * 256 + threadIdx.x; // 8192
    int b = idx >> 10, d = idx & 1023;
    float s = 0.f;
    for (int nz = 0; nz < 8; ++nz) s += pmean[(b * 8 + nz) * DD + d];
    mean[idx] = s * (1.f / 512.f);
}

// ---------------- K3a: sinusoidal embedding (f64 arg path matches reference) ----------------
__global__ void emb_kernel(const int* __restrict__ t, float* __restrict__ embf) {
    int idx = blockIdx.x * 256 + threadIdx.x; // 8192
    int b = idx >> 10, j = idx & 1023;
    int jj = j & 511;
    double arg = (double)t[b] * exp((-log(10000.0) / 511.0) * (double)jj);
    embf[idx] = (float)((j < 512) ? sin(arg) : cos(arg));
}

// ---------------- K2c: ctx_bn = mean @ ctx_w + ctx_b ----------------
__global__ void ctxbn_kernel(const float* __restrict__ mean, const float* __restrict__ ctx_w,
                             const float* __restrict__ ctx_b, float* __restrict__ ctx_bn) {
    __shared__ float red[8][32];
    int b = blockIdx.x >> 3, cg = blockIdx.x & 7;
    int c = cg * 32 + (threadIdx.x & 31), ks = threadIdx.x >> 5;
    const float* mb = mean + b * DD + ks * 128;
    const float* wb = ctx_w + (size_t)(ks * 128) * 256 + c;
    float acc = 0.f;
    for (int i = 0; i < 128; ++i) acc += mb[i] * wb[(size_t)i * 256];
    red[ks][threadIdx.x & 31] = acc;
    __syncthreads();
    if (threadIdx.x < 32) {
        float s = 0.f;
        for (int k = 0; k < 8; ++k) s += red[k][threadIdx.x];
        ctx_bn[b * 256 + cg * 32 + threadIdx.x] = s + ctx_b[cg * 32 + threadIdx.x];
    }
}

// ---------------- K3b: t_emb = emb @ t_proj_w + t_proj_b ----------------
__global__ void temb_kernel(const float* __restrict__ embf, const float* __restrict__ tpw,
                            const float* __restrict__ tpb, float* __restrict__ t_emb) {
    __shared__ float red[4][64];
    int b = blockIdx.x, cg = blockIdx.y;
    int c = cg * 64 + (threadIdx.x & 63), ks = threadIdx.x >> 6;
    const float* eb = embf + b * DD + ks * 256;
    const float* wb = tpw + (size_t)(ks * 256) * DD + c;
    float acc = 0.f;
    for (int i = 0; i < 256; ++i) acc += eb[i] * wb[(size_t)i * DD];
    red[ks][threadIdx.x & 63] = acc;
    __syncthreads();
    if (threadIdx.x < 64) {
        float s = red[0][threadIdx.x] + red[1][threadIdx.x] + red[2][threadIdx.x] + red[3][threadIdx.x];
        t_emb[b * DD + cg * 64 + threadIdx.x] = s + tpb[cg * 64 + threadIdx.x];
    }
}

// ---------------- K4: base_h = b1 + ctx_bn@w1[1024:1280] + t_emb@w1[1280:2304] ----------------
__global__ void baseh_kernel(const float* __restrict__ ctx_bn, const float* __restrict__ t_emb,
                             const float* __restrict__ w1, const float* __restrict__ b1,
                             float* __restrict__ base_h) {
    __shared__ float red[8][32];
    int b = blockIdx.x, cg = blockIdx.y;
    int c = cg * 32 + (threadIdx.x & 31), ks = threadIdx.x >> 5;
    float acc = 0.f;
    for (int i = 0; i < 160; ++i) {
        int k = ks * 160 + i;
        float v = (k < 256) ? ctx_bn[b * 256 + k] : t_emb[b * DD + k - 256];
        acc += v * w1[(size_t)(1024 + k) * H1 + c];
    }
    red[ks][threadIdx.x & 31] = acc;
    __syncthreads();
    if (threadIdx.x < 32) {
        float s = 0.f;
        for (int k = 0; k < 8; ++k) s += red[k][threadIdx.x];
        base_h[b * H1 + cg * 32 + threadIdx.x] = s + b1[cg * 32 + threadIdx.x];
    }
}

// ---------------- K5: MFMA GEMM, 128 rows x all 512 cols per block, fused relu*w2 reduce ----------------
// 512 thr = 8 waves (2 wm x 4 wn); wave owns 64 rows x 128 cols = 4x8 frags of 16x16x32 bf16.
__global__ __launch_bounds__(512, 2) void gemm_kernel(
    const float* __restrict__ tokens, const unsigned short* __restrict__ w1t,
    const float* __restrict__ baseh, const float* __restrict__ w2,
    float* __restrict__ part) {
    __shared__ unsigned short As[128 * 40]; // stride 40 bf16 = 80B: conflict-free frag reads
    __shared__ unsigned short Bs[512 * 40];
    __shared__ float red[128][4];
    int tid = threadIdx.x;
    int lane = tid & 63, wid = tid >> 6;
    int wm = wid >> 2, wn = wid & 3;
    int la = lane & 15, lk = lane >> 4;
    int row0 = blockIdx.x * 128;

    f32x4 acc[4][8];
    #pragma unroll
    for (int i = 0; i < 4; ++i)
        #pragma unroll
        for (int j = 0; j < 8; ++j)
            acc[i][j] = (f32x4){0.f, 0.f, 0.f, 0.f};

    for (int kt = 0; kt < DD; kt += 32) {
        // stage A: 128x32 f32 -> bf16, two float4 per thread
        #pragma unroll
        for (int i = 0; i < 2; ++i) {
            int id = tid + 512 * i;
            int r = id >> 3, xk = id & 7;
            float4 v = *(const float4*)(tokens + (size_t)(row0 + r) * DD + kt + xk * 4);
            ushort4 h;
            h.x = f2bf(v.x); h.y = f2bf(v.y); h.z = f2bf(v.z); h.w = f2bf(v.w);
            *(ushort4*)(As + r * 40 + xk * 4) = h;
        }
        // stage B: 512x32 bf16 tile from pre-transposed w1t, four 16B chunks per thread
        #pragma unroll
        for (int i = 0; i < 4; ++i) {
            int id = tid + 512 * i;
            int c = id >> 2, xk = id & 3;
            uint4 v = *(const uint4*)(w1t + (size_t)c * DD + kt + xk * 8);
            *(uint4*)(Bs + c * 40 + xk * 8) = v;
        }
        __syncthreads();
        bf16x8 af[4], bfr[8];
        #pragma unroll
        for (int mf = 0; mf < 4; ++mf) {
            int r = wm * 64 + mf * 16 + la;
            af[mf] = *(const bf16x8*)(As + r * 40 + lk * 8);
        }
        #pragma unroll
        for (int nf = 0; nf < 8; ++nf) {
            int c = wn * 128 + nf * 16 + la;
            bfr[nf] = *(const bf16x8*)(Bs + c * 40 + lk * 8);
        }
        #pragma unroll
        for (int mf = 0; mf < 4; ++mf)
            #pragma unroll
            for (int nf = 0; nf < 8; ++nf)
                acc[mf][nf] = __builtin_amdgcn_mfma_f32_16x16x32_bf16(af[mf], bfr[nf], acc[mf][nf], 0, 0, 0);
        __syncthreads();
    }

    // epilogue: h = acc + baseh[col]; relu; * w2[col]; row-reduce
    int b = row0 >> 12;
    const float* bh = baseh + b * H1;
    float bhv[8], w2v[8];
    #pragma unroll
    for (int nf = 0; nf < 8; ++nf) {
        int col = wn * 128 + nf * 16 + la;
        bhv[nf] = bh[col];
        w2v[nf] = w2[col];
    }
    #pragma unroll
    for (int mf = 0; mf < 4; ++mf) {
        #pragma unroll
        for (int reg = 0; reg < 4; ++reg) {
            float p = 0.f;
            #pragma unroll
            for (int nf = 0; nf < 8; ++nf) {
                float h = acc[mf][nf][reg] + bhv[nf];
                h = fmaxf(h, 0.f);
                p += h * w2v[nf];
            }
            p += __shfl_xor(p, 1, 64);
            p += __shfl_xor(p, 2, 64);
            p += __shfl_xor(p, 4, 64);
            p += __shfl_xor(p, 8, 64);
            if (la == 0) red[wm * 64 + mf * 16 + lk * 4 + reg][wn] = p;
        }
    }
    __syncthreads();
    if (tid < 128)
        part[row0 + tid] = red[tid][0] + red[tid][1] + red[tid][2] + red[tid][3];
}

// ---------------- K6: score + pre-floor skip ----------------
__global__ void score_kernel(const float* __restrict__ part, const float* __restrict__ b2,
                             const void* __restrict__ rare, const int* __restrict__ mode_p,
                             float* __restrict__ out) {
    int row = blockIdx.x * 256 + threadIdx.x;
    float logit = part[row] + b2[0];
    float score = 1.f / (1.f + expf(-logit));
    int mode = *mode_p;
    bool rm = (mode == 1) ? (((const unsigned char*)rare)[row] != 0)
            : (mode == 2) ? (((const float*)rare)[row] != 0.f)
            : (((const int*)rare)[row] != 0);
    out[row] = ((score > 0.5f) && !rm) ? 1.f : 0.f;
    out[M_TOT + row] = score;
}

// ---------------- K7: exact f32 recompute for |logit| < MARGIN rows ----------------
__global__ __launch_bounds__(512) void fixup_kernel(
    const float* __restrict__ part, const float* __restrict__ b2,
    const float* __restrict__ tokens, const float* __restrict__ w1,
    const float* __restrict__ base_h, const float* __restrict__ w2,
    const void* __restrict__ rare, const int* __restrict__ mode_p,
    float* __restrict__ out) {
    __shared__ float red[512];
    __shared__ int rows[128];
    __shared__ int nrows;
    int tid = threadIdx.x;
    if (tid == 0) nrows = 0;
    __syncthreads();
    int r0 = blockIdx.x * 128; // 256 blocks cover 32768 rows
    if (tid < 128) {
        float lg = part[r0 + tid] + b2[0];
        if (fabsf(lg) < MARGIN) { int i = atomicAdd(&nrows, 1); rows[i] = r0 + tid; }
    }
    __syncthreads();
    int n = nrows;
    for (int g = 0; g < n; ++g) {
        int row = rows[g];
        int b = row >> 12;
        const float* tr = tokens + (size_t)row * DD;
        float acc = 0.f;
        for (int k = 0; k < DD; ++k) acc += tr[k] * w1[(size_t)k * H1 + tid];
        float h = acc + base_h[b * H1 + tid];
        h = fmaxf(h, 0.f);
        red[tid] = h * w2[tid];
        __syncthreads();
        for (int s = 256; s > 0; s >>= 1) {
            if (tid < s) red[tid] += red[tid + s];
            __syncthreads();
        }
        if (tid == 0) {
            float logit = red[0] + b2[0];
            float score = 1.f / (1.f + expf(-logit));
            int mode = *mode_p;
            bool rm = (mode == 1) ? (((const unsigned char*)rare)[row] != 0)
                    : (mode == 2) ? (((const float*)rare)[row] != 0.f)
                    : (((const int*)rare)[row] != 0);
            out[row] = ((score > 0.5f) && !rm) ? 1.f : 0.f;
            out[M_TOT + row] = score;
        }
        __syncthreads();
    }
}

// ---------------- K8: 20% active-floor correction ----------------
__global__ void floor_kernel(float* __restrict__ out) {
    __shared__ float s[NN];
    __shared__ unsigned char f[NN];
    __shared__ int cnt;
    int b = blockIdx.x, tid = threadIdx.x;
    if (tid == 0) cnt = 0;
    __syncthreads();
    int local = 0;
    for (int i = tid; i < NN; i += 256) {
        s[i] = out[M_TOT + b * NN + i];
        unsigned char sk = out[b * NN + i] > 0.5f;
        f[i] = sk;
        local += sk;
    }
    atomicAdd(&cnt, local);
    __syncthreads();
    int deficit = cnt - (NN - MIN_ACTIVE);
    if (deficit <= 0) return;
    for (int i = tid; i < NN; i += 256) {
        if (!f[i]) continue;
        float si = s[i];
        int rank = 0;
        for (int j = 0; j < NN; ++j) {
            if (f[j] && (s[j] < si || (s[j] == si && j < i))) {
                if (++rank >= deficit) break;
            }
        }
        if (rank < deficit) out[b * NN + i] = 0.f;
    }
}

extern "C" void kernel_launch(void* const* d_in, const int* in_sizes, int n_in,
                              void* d_out, int out_size, void* d_ws, size_t ws_size,
                              hipStream_t stream) {
    const float* tokens   = (const float*)d_in[0];
    const float* ctx_C    = (const float*)d_in[1];
    const int*   t        = (const int*)d_in[2];
    const void*  rare     = d_in[3];
    const float* ctx_w    = (const float*)d_in[4];
    const float* ctx_b    = (const float*)d_in[5];
    const float* t_proj_w = (const float*)d_in[6];
    const float* t_proj_b = (const float*)d_in[7];
    const float* w1       = (const float*)d_in[8];
    const float* b1       = (const float*)d_in[9];
    const float* w2       = (const float*)d_in[10];
    const float* b2       = (const float*)d_in[11];
    float* out = (float*)d_out;

    char* ws = (char*)d_ws;
    unsigned short* w1t   = (unsigned short*)(ws);                 // 1,048,576 B
    float* pmean          = (float*)(ws + 1048576);                // 262,144 B
    float* mean           = (float*)(ws + 1310720);                // 32,768 B
    float* embf           = (float*)(ws + 1343488);                // 32,768 B
    float* ctx_bn         = (float*)(ws + 1376256);                // 8,192 B
    float* t_emb          = (float*)(ws + 1384448);                // 32,768 B
    float* base_h         = (float*)(ws + 1417216);                // 16,384 B
    float* part           = (float*)(ws + 1433600);                // 131,072 B
    int*   mode           = (int*)  (ws + 1564672);                // 4 B

    detect_mask_kernel<<<1, 256, 0, stream>>>((const unsigned char*)rare, mode);
    convB_kernel<<<512, 256, 0, stream>>>(w1, w1t);
    pmean_kernel<<<256, 256, 0, stream>>>(ctx_C, pmean);
    meanred_kernel<<<32, 256, 0, stream>>>(pmean, mean);
    emb_kernel<<<32, 256, 0, stream>>>(t, embf);
    ctxbn_kernel<<<64, 256, 0, stream>>>(mean, ctx_w, ctx_b, ctx_bn);
    temb_kernel<<<dim3(8, 16), 256, 0, stream>>>(embf, t_proj_w, t_proj_b, t_emb);
    baseh_kernel<<<dim3(8, 16), 256, 0, stream>>>(ctx_bn, t_emb, w1, b1, base_h);
    gemm_kernel<<<256, 512, 0, stream>>>(tokens, w1t, base_h, w2, part);
    score_kernel<<<128, 256, 0, stream>>>(part, b2, rare, mode, out);
    fixup_kernel<<<256, 512, 0, stream>>>(part, b2, tokens, w1, base_h, w2, rare, mode, out);
    floor_kernel<<<8, 256, 0, stream>>>(out);
}

// Round 3
// 222.759 us; speedup vs baseline: 3.5410x; 1.7432x over previous
//
#include <hip/hip_runtime.h>
#include <math.h>

#define NN 4096
#define DD 1024
#define M_TOT 32768
#define H1 512
#define MIN_ACTIVE 819
#define MARGIN 0.03f
#define MAXFIX 8192

typedef __bf16 bf16x8 __attribute__((ext_vector_type(8)));
typedef float f32x4 __attribute__((ext_vector_type(4)));

__device__ __forceinline__ unsigned short f2bf(float f) {
    unsigned int u = __float_as_uint(f);
    return (unsigned short)((u + 0x7FFFu + ((u >> 16) & 1u)) >> 16);
}

// ---------------- K0: detect rare_mask storage format + zero fixup counter ----------------
__global__ void detect_mask_kernel(const unsigned char* __restrict__ p, int* __restrict__ mode,
                                   int* __restrict__ fixcnt) {
    __shared__ int nonbin, oneoff;
    if (threadIdx.x == 0) { nonbin = 0; oneoff = 0; *fixcnt = 0; }
    __syncthreads();
    int lnon = 0, lone = 0;
    for (int i = threadIdx.x; i < 32768; i += blockDim.x) {
        unsigned char b = p[i];
        if (b > 1) lnon = 1;
        else if (b == 1 && (i & 3) != 0) lone = 1;
    }
    if (lnon) atomicOr(&nonbin, 1);
    if (lone) atomicOr(&oneoff, 1);
    __syncthreads();
    if (threadIdx.x == 0) *mode = nonbin ? 2 : (oneoff ? 1 : 0);
}

// ---------------- K1: transpose+convert w1[0:1024][:512] -> bf16 [512][1024] ----------------
__global__ void convB_kernel(const float* __restrict__ w1, unsigned short* __restrict__ w1t) {
    __shared__ float tile[32][33];
    int k0 = (blockIdx.x >> 4) * 32;
    int c0 = (blockIdx.x & 15) * 32;
    int tid = threadIdx.x;
    int cl = tid & 31, r8 = tid >> 5;
    #pragma unroll
    for (int i = 0; i < 4; ++i) {
        int kl = r8 + 8 * i;
        tile[kl][cl] = w1[(size_t)(k0 + kl) * H1 + c0 + cl];
    }
    __syncthreads();
    #pragma unroll
    for (int i = 0; i < 4; ++i) {
        int cr = r8 + 8 * i;
        w1t[(size_t)(c0 + cr) * DD + k0 + cl] = f2bf(tile[cl][cr]);
    }
}

// ---------------- K2a: partial ctx mean ----------------
__global__ void pmean_kernel(const float* __restrict__ ctx, float* __restrict__ pmean) {
    int blk = blockIdx.x; // 256 = 8b * 4dq * 8nz
    int b = blk >> 5, dq = (blk >> 3) & 3, nz = blk & 7;
    int d = dq * 256 + threadIdx.x;
    const float* base = ctx + ((size_t)(b * 512 + nz * 64)) * DD + d;
    float acc = 0.f;
    for (int n = 0; n < 64; ++n) acc += base[(size_t)n * DD];
    pmean[(b * 8 + nz) * DD + d] = acc;
}

// ---------------- K2b: reduce partials -> mean ----------------
__global__ void meanred_kernel(const float* __restrict__ pmean, float* __restrict__ mean) {
    int idx = blockIdx.x * 256 + threadIdx.x; // 8192
    int b = idx >> 10, d = idx & 1023;
    float s = 0.f;
    for (int nz = 0; nz < 8; ++nz) s += pmean[(b * 8 + nz) * DD + d];
    mean[idx] = s * (1.f / 512.f);
}

// ---------------- K3a: sinusoidal embedding (f64 arg path matches reference) ----------------
__global__ void emb_kernel(const int* __restrict__ t, float* __restrict__ embf) {
    int idx = blockIdx.x * 256 + threadIdx.x; // 8192
    int b = idx >> 10, j = idx & 1023;
    int jj = j & 511;
    double arg = (double)t[b] * exp((-log(10000.0) / 511.0) * (double)jj);
    embf[idx] = (float)((j < 512) ? sin(arg) : cos(arg));
}

// ---------------- K2c: ctx_bn = mean @ ctx_w + ctx_b ----------------
__global__ void ctxbn_kernel(const float* __restrict__ mean, const float* __restrict__ ctx_w,
                             const float* __restrict__ ctx_b, float* __restrict__ ctx_bn) {
    __shared__ float red[8][32];
    int b = blockIdx.x >> 3, cg = blockIdx.x & 7;
    int c = cg * 32 + (threadIdx.x & 31), ks = threadIdx.x >> 5;
    const float* mb = mean + b * DD + ks * 128;
    const float* wb = ctx_w + (size_t)(ks * 128) * 256 + c;
    float acc = 0.f;
    for (int i = 0; i < 128; ++i) acc += mb[i] * wb[(size_t)i * 256];
    red[ks][threadIdx.x & 31] = acc;
    __syncthreads();
    if (threadIdx.x < 32) {
        float s = 0.f;
        for (int k = 0; k < 8; ++k) s += red[k][threadIdx.x];
        ctx_bn[b * 256 + cg * 32 + threadIdx.x] = s + ctx_b[cg * 32 + threadIdx.x];
    }
}

// ---------------- K3b: t_emb = emb @ t_proj_w + t_proj_b ----------------
__global__ void temb_kernel(const float* __restrict__ embf, const float* __restrict__ tpw,
                            const float* __restrict__ tpb, float* __restrict__ t_emb) {
    __shared__ float red[4][64];
    int b = blockIdx.x, cg = blockIdx.y;
    int c = cg * 64 + (threadIdx.x & 63), ks = threadIdx.x >> 6;
    const float* eb = embf + b * DD + ks * 256;
    const float* wb = tpw + (size_t)(ks * 256) * DD + c;
    float acc = 0.f;
    for (int i = 0; i < 256; ++i) acc += eb[i] * wb[(size_t)i * DD];
    red[ks][threadIdx.x & 63] = acc;
    __syncthreads();
    if (threadIdx.x < 64) {
        float s = red[0][threadIdx.x] + red[1][threadIdx.x] + red[2][threadIdx.x] + red[3][threadIdx.x];
        t_emb[b * DD + cg * 64 + threadIdx.x] = s + tpb[cg * 64 + threadIdx.x];
    }
}

// ---------------- K4: base_h = b1 + ctx_bn@w1[1024:1280] + t_emb@w1[1280:2304] ----------------
__global__ void baseh_kernel(const float* __restrict__ ctx_bn, const float* __restrict__ t_emb,
                             const float* __restrict__ w1, const float* __restrict__ b1,
                             float* __restrict__ base_h) {
    __shared__ float red[8][32];
    int b = blockIdx.x, cg = blockIdx.y;
    int c = cg * 32 + (threadIdx.x & 31), ks = threadIdx.x >> 5;
    float acc = 0.f;
    for (int i = 0; i < 160; ++i) {
        int k = ks * 160 + i;
        float v = (k < 256) ? ctx_bn[b * 256 + k] : t_emb[b * DD + k - 256];
        acc += v * w1[(size_t)(1024 + k) * H1 + c];
    }
    red[ks][threadIdx.x & 31] = acc;
    __syncthreads();
    if (threadIdx.x < 32) {
        float s = 0.f;
        for (int k = 0; k < 8; ++k) s += red[k][threadIdx.x];
        base_h[b * H1 + cg * 32 + threadIdx.x] = s + b1[cg * 32 + threadIdx.x];
    }
}

// ---------------- K5: MFMA GEMM, 128 rows x all 512 cols per block, fused relu*w2 reduce ----------------
__global__ __launch_bounds__(512, 2) void gemm_kernel(
    const float* __restrict__ tokens, const unsigned short* __restrict__ w1t,
    const float* __restrict__ baseh, const float* __restrict__ w2,
    float* __restrict__ part) {
    __shared__ unsigned short As[128 * 40];
    __shared__ unsigned short Bs[512 * 40];
    __shared__ float red[128][4];
    int tid = threadIdx.x;
    int lane = tid & 63, wid = tid >> 6;
    int wm = wid >> 2, wn = wid & 3;
    int la = lane & 15, lk = lane >> 4;
    int row0 = blockIdx.x * 128;

    f32x4 acc[4][8];
    #pragma unroll
    for (int i = 0; i < 4; ++i)
        #pragma unroll
        for (int j = 0; j < 8; ++j)
            acc[i][j] = (f32x4){0.f, 0.f, 0.f, 0.f};

    for (int kt = 0; kt < DD; kt += 32) {
        #pragma unroll
        for (int i = 0; i < 2; ++i) {
            int id = tid + 512 * i;
            int r = id >> 3, xk = id & 7;
            float4 v = *(const float4*)(tokens + (size_t)(row0 + r) * DD + kt + xk * 4);
            ushort4 h;
            h.x = f2bf(v.x); h.y = f2bf(v.y); h.z = f2bf(v.z); h.w = f2bf(v.w);
            *(ushort4*)(As + r * 40 + xk * 4) = h;
        }
        #pragma unroll
        for (int i = 0; i < 4; ++i) {
            int id = tid + 512 * i;
            int c = id >> 2, xk = id & 3;
            uint4 v = *(const uint4*)(w1t + (size_t)c * DD + kt + xk * 8);
            *(uint4*)(Bs + c * 40 + xk * 8) = v;
        }
        __syncthreads();
        bf16x8 af[4], bfr[8];
        #pragma unroll
        for (int mf = 0; mf < 4; ++mf) {
            int r = wm * 64 + mf * 16 + la;
            af[mf] = *(const bf16x8*)(As + r * 40 + lk * 8);
        }
        #pragma unroll
        for (int nf = 0; nf < 8; ++nf) {
            int c = wn * 128 + nf * 16 + la;
            bfr[nf] = *(const bf16x8*)(Bs + c * 40 + lk * 8);
        }
        #pragma unroll
        for (int mf = 0; mf < 4; ++mf)
            #pragma unroll
            for (int nf = 0; nf < 8; ++nf)
                acc[mf][nf] = __builtin_amdgcn_mfma_f32_16x16x32_bf16(af[mf], bfr[nf], acc[mf][nf], 0, 0, 0);
        __syncthreads();
    }

    int b = row0 >> 12;
    const float* bh = baseh + b * H1;
    float bhv[8], w2v[8];
    #pragma unroll
    for (int nf = 0; nf < 8; ++nf) {
        int col = wn * 128 + nf * 16 + la;
        bhv[nf] = bh[col];
        w2v[nf] = w2[col];
    }
    #pragma unroll
    for (int mf = 0; mf < 4; ++mf) {
        #pragma unroll
        for (int reg = 0; reg < 4; ++reg) {
            float p = 0.f;
            #pragma unroll
            for (int nf = 0; nf < 8; ++nf) {
                float h = acc[mf][nf][reg] + bhv[nf];
                h = fmaxf(h, 0.f);
                p += h * w2v[nf];
            }
            p += __shfl_xor(p, 1, 64);
            p += __shfl_xor(p, 2, 64);
            p += __shfl_xor(p, 4, 64);
            p += __shfl_xor(p, 8, 64);
            if (la == 0) red[wm * 64 + mf * 16 + lk * 4 + reg][wn] = p;
        }
    }
    __syncthreads();
    if (tid < 128)
        part[row0 + tid] = red[tid][0] + red[tid][1] + red[tid][2] + red[tid][3];
}

// ---------------- K6: score + pre-floor skip + marginal-row compaction ----------------
__global__ void score_kernel(const float* __restrict__ part, const float* __restrict__ b2,
                             const void* __restrict__ rare, const int* __restrict__ mode_p,
                             float* __restrict__ out, int* __restrict__ fixcnt,
                             int* __restrict__ fixlist) {
    int row = blockIdx.x * 256 + threadIdx.x;
    float logit = part[row] + b2[0];
    float score = 1.f / (1.f + expf(-logit));
    int mode = *mode_p;
    bool rm = (mode == 1) ? (((const unsigned char*)rare)[row] != 0)
            : (mode == 2) ? (((const float*)rare)[row] != 0.f)
            : (((const int*)rare)[row] != 0);
    out[row] = ((score > 0.5f) && !rm) ? 1.f : 0.f;
    out[M_TOT + row] = score;
    if (fabsf(logit) < MARGIN) {
        int i = atomicAdd(fixcnt, 1);
        if (i < MAXFIX) fixlist[i] = row;
    }
}

// ---------------- K7: exact f32 recompute for marginal rows (1 row per block pass) ----------------
__global__ __launch_bounds__(512) void fixup_kernel(
    const int* __restrict__ fixcnt, const int* __restrict__ fixlist,
    const float* __restrict__ tokens, const float* __restrict__ w1,
    const float* __restrict__ base_h, const float* __restrict__ w2,
    const float* __restrict__ b2, const void* __restrict__ rare,
    const int* __restrict__ mode_p, float* __restrict__ out) {
    __shared__ float tok[DD];
    __shared__ float red[8];
    int tid = threadIdx.x;
    int lane = tid & 63, wid = tid >> 6;
    int n = *fixcnt;
    if (n > MAXFIX) n = MAXFIX;
    for (int g = blockIdx.x; g < n; g += gridDim.x) {
        int row = fixlist[g];
        int b = row >> 12;
        if (tid < 256)
            ((float4*)tok)[tid] = ((const float4*)(tokens + (size_t)row * DD))[tid];
        __syncthreads();
        float acc = 0.f;
        const float* wp = w1 + tid;
        #pragma unroll 8
        for (int k = 0; k < DD; ++k)
            acc += tok[k] * wp[(size_t)k * H1];
        float h = acc + base_h[b * H1 + tid];
        h = fmaxf(h, 0.f);
        float p = h * w2[tid];
        p += __shfl_xor(p, 1, 64);
        p += __shfl_xor(p, 2, 64);
        p += __shfl_xor(p, 4, 64);
        p += __shfl_xor(p, 8, 64);
        p += __shfl_xor(p, 16, 64);
        p += __shfl_xor(p, 32, 64);
        if (lane == 0) red[wid] = p;
        __syncthreads();
        if (tid == 0) {
            float logit = b2[0];
            #pragma unroll
            for (int w = 0; w < 8; ++w) logit += red[w];
            float score = 1.f / (1.f + expf(-logit));
            int mode = *mode_p;
            bool rm = (mode == 1) ? (((const unsigned char*)rare)[row] != 0)
                    : (mode == 2) ? (((const float*)rare)[row] != 0.f)
                    : (((const int*)rare)[row] != 0);
            out[row] = ((score > 0.5f) && !rm) ? 1.f : 0.f;
            out[M_TOT + row] = score;
        }
        __syncthreads();
    }
}

// ---------------- K8: 20% active-floor correction ----------------
__global__ void floor_kernel(float* __restrict__ out) {
    __shared__ float s[NN];
    __shared__ unsigned char f[NN];
    __shared__ int cnt;
    int b = blockIdx.x, tid = threadIdx.x;
    if (tid == 0) cnt = 0;
    __syncthreads();
    int local = 0;
    for (int i = tid; i < NN; i += 256) {
        s[i] = out[M_TOT + b * NN + i];
        unsigned char sk = out[b * NN + i] > 0.5f;
        f[i] = sk;
        local += sk;
    }
    atomicAdd(&cnt, local);
    __syncthreads();
    int deficit = cnt - (NN - MIN_ACTIVE);
    if (deficit <= 0) return;
    for (int i = tid; i < NN; i += 256) {
        if (!f[i]) continue;
        float si = s[i];
        int rank = 0;
        for (int j = 0; j < NN; ++j) {
            if (f[j] && (s[j] < si || (s[j] == si && j < i))) {
                if (++rank >= deficit) break;
            }
        }
        if (rank < deficit) out[b * NN + i] = 0.f;
    }
}

extern "C" void kernel_launch(void* const* d_in, const int* in_sizes, int n_in,
                              void* d_out, int out_size, void* d_ws, size_t ws_size,
                              hipStream_t stream) {
    const float* tokens   = (const float*)d_in[0];
    const float* ctx_C    = (const float*)d_in[1];
    const int*   t        = (const int*)d_in[2];
    const void*  rare     = d_in[3];
    const float* ctx_w    = (const float*)d_in[4];
    const float* ctx_b    = (const float*)d_in[5];
    const float* t_proj_w = (const float*)d_in[6];
    const float* t_proj_b = (const float*)d_in[7];
    const float* w1       = (const float*)d_in[8];
    const float* b1       = (const float*)d_in[9];
    const float* w2       = (const float*)d_in[10];
    const float* b2       = (const float*)d_in[11];
    float* out = (float*)d_out;

    char* ws = (char*)d_ws;
    unsigned short* w1t   = (unsigned short*)(ws);                 // 1,048,576 B
    float* pmean          = (float*)(ws + 1048576);                // 262,144 B
    float* mean           = (float*)(ws + 1310720);                // 32,768 B
    float* embf           = (float*)(ws + 1343488);                // 32,768 B
    float* ctx_bn         = (float*)(ws + 1376256);                // 8,192 B
    float* t_emb          = (float*)(ws + 1384448);                // 32,768 B
    float* base_h         = (float*)(ws + 1417216);                // 16,384 B
    float* part           = (float*)(ws + 1433600);                // 131,072 B
    int*   mode           = (int*)  (ws + 1564672);                // 4 B
    int*   fixcnt         = (int*)  (ws + 1564736);                // 4 B
    int*   fixlist        = (int*)  (ws + 1564800);                // 32,768 B

    detect_mask_kernel<<<1, 256, 0, stream>>>((const unsigned char*)rare, mode, fixcnt);
    convB_kernel<<<512, 256, 0, stream>>>(w1, w1t);
    pmean_kernel<<<256, 256, 0, stream>>>(ctx_C, pmean);
    meanred_kernel<<<32, 256, 0, stream>>>(pmean, mean);
    emb_kernel<<<32, 256, 0, stream>>>(t, embf);
    ctxbn_kernel<<<64, 256, 0, stream>>>(mean, ctx_w, ctx_b, ctx_bn);
    temb_kernel<<<dim3(8, 16), 256, 0, stream>>>(embf, t_proj_w, t_proj_b, t_emb);
    baseh_kernel<<<dim3(8, 16), 256, 0, stream>>>(ctx_bn, t_emb, w1, b1, base_h);
    gemm_kernel<<<256, 512, 0, stream>>>(tokens, w1t, base_h, w2, part);
    score_kernel<<<128, 256, 0, stream>>>(part, b2, rare, mode, out, fixcnt, fixlist);
    fixup_kernel<<<512, 512, 0, stream>>>(fixcnt, fixlist, tokens, w1, base_h, w2, b2, rare, mode, out);
    floor_kernel<<<8, 256, 0, stream>>>(out);
}